// Round 1
// 119.138 us; speedup vs baseline: 1.0308x; 1.0308x over previous
//
#include <hip/hip_runtime.h>
#include <stdint.h>

#define T_ROWS 16384
#define D_DIM  256
#define N_CODES 8192
#define NSPLIT 4
#define NS (N_CODES / NSPLIT)   // 2048
#define NCHUNK (NS / 128)       // 16
#define NITER (NCHUNK * 8)      // 128 k-steps

typedef _Float16 h8v __attribute__((ext_vector_type(8)));
typedef float f4v __attribute__((ext_vector_type(4)));
typedef unsigned short u16;
typedef unsigned int u32;
typedef unsigned long long u64;

typedef const __attribute__((address_space(1))) uint32_t* as1_t;
typedef __attribute__((address_space(3))) uint32_t* as3_t;

__device__ __forceinline__ void gload_lds16(const void* g, void* l) {
    __builtin_amdgcn_global_load_lds((as1_t)(uintptr_t)g, (as3_t)(uintptr_t)l, 16, 0, 0);
}
__device__ __forceinline__ u32 umin32(u32 a, u32 b) { return a < b ? a : b; }
__device__ __forceinline__ u32 umax32(u32 a, u32 b) { return a > b ? a : b; }

// ---------------- emb: fp32 -> fp16 + squared norm (+1024 shift for u32-key trick) ----------------
__global__ void k_prep_emb(const float* __restrict__ emb, u16* __restrict__ Ef,
                           float* __restrict__ enormP) {
    int wv = threadIdx.x >> 6, lane = threadIdx.x & 63;
    int row = blockIdx.x * 4 + wv;
    float4 v = *reinterpret_cast<const float4*>(emb + (size_t)row * D_DIM + lane * 4);
    float s = v.x * v.x + v.y * v.y + v.z * v.z + v.w * v.w;
    ushort4 h;
    { _Float16 t0=(_Float16)v.x,t1=(_Float16)v.y,t2=(_Float16)v.z,t3=(_Float16)v.w;
      h.x=*reinterpret_cast<u16*>(&t0); h.y=*reinterpret_cast<u16*>(&t1);
      h.z=*reinterpret_cast<u16*>(&t2); h.w=*reinterpret_cast<u16*>(&t3); }
    reinterpret_cast<ushort4*>(Ef + (size_t)row * D_DIM)[lane] = h;
#pragma unroll
    for (int off = 32; off; off >>= 1) s += __shfl_xor(s, off, 64);
    if (lane == 0) enormP[row] = s + 1024.0f;   // shift keeps all scores > 0
}

// ---------------- fp16 MFMA approx-score, A-in-registers ----------------
// Round-2 restructure: within-wave ds_read/MFMA software pipeline.
//  - 4 LDS buffers (was 3); stage(it+3) issued each step; "vmcnt(2); s_barrier" at
//    step TOP guarantees stage(it+1) complete -> B frags for step it+1 prefetched
//    into a ping-pong register set BEFORE the MFMAs of step it (ds latency hides
//    under MFMA instead of serializing via lgkmcnt(0) drain).
//  - write-slot (it+3)%4 was last ds_read two barriers earlier -> race-free.
//  - en loads issued AFTER the top-of-step wait (so vmcnt(2) doesn't drain them early).
__global__ __launch_bounds__(256, 2)
void k_main_mfma(const float* __restrict__ x, const u16* __restrict__ Ef,
                 const float* __restrict__ enormP, u32* __restrict__ cand) {
    __shared__ u16 Bs[4][4096];   // 4 x (128 rows x 32 k fp16) = 32 KB

    const int tid = threadIdx.x;
    const int lane = tid & 63;
    const int w = tid >> 6;
    const int c15 = lane & 15, grp = lane >> 4;
    const int m0 = (int)(blockIdx.x >> 2) * 128;
    const int split = (int)(blockIdx.x & 3);
    const int nbase = split * NS;

    // B read offsets (proven 0-conflict pattern)
    int boff[8];
#pragma unroll
    for (int ni = 0; ni < 8; ++ni) {
        int r = ni * 16 + c15;
        boff[ni] = (r * 64 + grp * 16) ^ (((r >> 1) & 3) << 4);
    }
    // B staging addressing (proven)
    const int srow = tid >> 2;
    const int kkb = ((tid & 3) ^ ((srow >> 1) & 3)) * 8;

    // ---- A fragments: load fp32 x, convert to fp16 in registers (one-time) ----
    h8v a[2][8];
#pragma unroll
    for (int mi = 0; mi < 2; ++mi)
#pragma unroll
        for (int ks = 0; ks < 8; ++ks) {
            const float* p = x + (size_t)(m0 + w * 32 + mi * 16 + c15) * D_DIM + ks * 32 + grp * 8;
            float4 u0 = *reinterpret_cast<const float4*>(p);
            float4 u1 = *reinterpret_cast<const float4*>(p + 4);
            h8v av;
            av[0] = (_Float16)u0.x; av[1] = (_Float16)u0.y;
            av[2] = (_Float16)u0.z; av[3] = (_Float16)u0.w;
            av[4] = (_Float16)u1.x; av[5] = (_Float16)u1.y;
            av[6] = (_Float16)u1.z; av[7] = (_Float16)u1.w;
            a[mi][ks] = av;
        }

    auto stageB = [&](int buf, int it) {
        const int nc = it >> 3, ks = it & 7;
        const u16* src = Ef + (size_t)(nbase + nc * 128 + srow) * D_DIM + ks * 32 + kkb;
        gload_lds16(src, (char*)Bs + buf * 8192 + tid * 16);
        gload_lds16(src + 64 * D_DIM, (char*)Bs + buf * 8192 + 4096 + tid * 16);
    };

    u32 b1[8], b2[8];
#pragma unroll
    for (int l = 0; l < 8; ++l) { b1[l] = 0xFFFFFFFFu; b2[l] = 0xFFFFFFFFu; }

    // prologue: stages 0..2 in flight; wait stage(0) (6 outstanding -> 4), preload b_cur
    stageB(0, 0);
    stageB(1, 1);
    stageB(2, 2);
    asm volatile("s_waitcnt vmcnt(4)\n\ts_barrier" ::: "memory");

    h8v bcur[8], bnxt[8];
#pragma unroll
    for (int ni = 0; ni < 8; ++ni)
        bcur[ni] = *reinterpret_cast<const h8v*>((const char*)Bs + boff[ni]);

    f4v acc[2][8];
    float en[8];

    // one pipeline step: wait+barrier, stage it+3, prefetch B(it+1) into bn, MFMA with bc
    auto do_step = [&](int it, int ks, h8v (&bc)[8], h8v (&bn)[8]) {
        asm volatile("s_waitcnt vmcnt(2)\n\ts_barrier" ::: "memory");
        {
            int it3 = it + 3;
            if (it3 > NITER - 1) it3 = NITER - 1;   // clamp keeps vmcnt accounting uniform
            stageB((it + 3) & 3, it3);
        }
        if (ks == 0) {
            const int nc = it >> 3;
#pragma unroll
            for (int ni = 0; ni < 8; ++ni)
                en[ni] = enormP[nbase + nc * 128 + ni * 16 + c15];
        }
        // prefetch next step's B frags (slot (it+1)%4 guaranteed by this step's vmcnt(2))
        {
            const char* bsb = (const char*)Bs + ((it + 1) & 3) * 8192;
#pragma unroll
            for (int ni = 0; ni < 8; ++ni)
                bn[ni] = *reinterpret_cast<const h8v*>(bsb + boff[ni]);
        }
        __builtin_amdgcn_s_setprio(1);
#pragma unroll
        for (int mi = 0; mi < 2; ++mi)
#pragma unroll
            for (int ni = 0; ni < 8; ++ni)
                acc[mi][ni] = __builtin_amdgcn_mfma_f32_16x16x32_f16(
                    a[mi][ks], bc[ni], acc[mi][ni], 0, 0, 0);
        __builtin_amdgcn_s_setprio(0);

        if (ks == 7) {   // chunk epilogue: packed-key top-2 over chunk-slice mins
            const int nc = it >> 3;
#pragma unroll
            for (int mi = 0; mi < 2; ++mi)
#pragma unroll
                for (int r = 0; r < 4; ++r) {
                    const int l = mi * 4 + r;
                    u32 kmin = 0xFFFFFFFFu;
#pragma unroll
                    for (int ni = 0; ni < 8; ++ni) {
                        float s = fmaf(-2.0f, acc[mi][ni][r], en[ni]);   // > 0 by +1024 shift
                        u32 k = (__float_as_uint(s) & 0xFFFFF800u)
                              | (u32)(nc * 128 + ni * 16 + c15);
                        kmin = umin32(kmin, k);
                    }
                    b2[l] = umin32(b2[l], umax32(b1[l], kmin));
                    b1[l] = umin32(b1[l], kmin);
                }
        }
    };

    for (int nc = 0; nc < NCHUNK; ++nc) {
#pragma unroll
        for (int mi = 0; mi < 2; ++mi)
#pragma unroll
            for (int ni = 0; ni < 8; ++ni) acc[mi][ni] = f4v{0.f, 0.f, 0.f, 0.f};

#pragma unroll
        for (int kp = 0; kp < 4; ++kp) {
            do_step(nc * 8 + kp * 2 + 0, kp * 2 + 0, bcur, bnxt);
            do_step(nc * 8 + kp * 2 + 1, kp * 2 + 1, bnxt, bcur);
        }
    }

    // cross-lane top-2 merge (16 c15-lanes per grp; off<16 stays in group)
#pragma unroll
    for (int l = 0; l < 8; ++l) {
#pragma unroll
        for (int off = 1; off < 16; off <<= 1) {
            u32 o1 = __shfl_xor(b1[l], off, 64);
            u32 o2 = __shfl_xor(b2[l], off, 64);
            b2[l] = umin32(umax32(b1[l], o1), umin32(b2[l], o2));
            b1[l] = umin32(b1[l], o1);
        }
    }
    if (c15 == 0) {
#pragma unroll
        for (int mi = 0; mi < 2; ++mi)
#pragma unroll
            for (int r = 0; r < 4; ++r) {
                const int l = mi * 4 + r;
                const int grow = m0 + w * 32 + mi * 16 + grp * 4 + r;
                cand[grow * 8 + split * 2 + 0] = (u32)nbase + (b1[l] & 0x7FFu);
                cand[grow * 8 + split * 2 + 1] = (u32)nbase + (b2[l] & 0x7FFu);
            }
    }
}

// ---------------- fused refine + output: exact fp64 over 8 cands, 1 wave/row ----------------
__global__ void k_refine(const float* __restrict__ x, const float* __restrict__ emb,
                         const u32* __restrict__ cand, float* __restrict__ out,
                         double* __restrict__ partials) {
    const int tid = threadIdx.x;
    const int wv = tid >> 6, lane = tid & 63;
    const int row = blockIdx.x * 4 + wv;
    const int cslot = lane >> 3, sub = lane & 7;
    int idx = (int)cand[row * 8 + cslot];
    double d = 0.0;
#pragma unroll
    for (int j = 0; j < 8; ++j) {
        float4 xv = *reinterpret_cast<const float4*>(x + (size_t)row * D_DIM + sub * 32 + j * 4);
        float4 ev = *reinterpret_cast<const float4*>(emb + (size_t)idx * D_DIM + sub * 32 + j * 4);
        double d0 = (double)xv.x - (double)ev.x;
        double d1 = (double)xv.y - (double)ev.y;
        double d2 = (double)xv.z - (double)ev.z;
        double d3 = (double)xv.w - (double)ev.w;
        d += d0 * d0 + d1 * d1 + d2 * d2 + d3 * d3;
    }
#pragma unroll
    for (int off = 1; off < 8; off <<= 1) d += __shfl_xor(d, off, 64);   // within 8-lane group
    // cross-candidate butterfly: all lanes end with the winner
#pragma unroll
    for (int off = 8; off < 64; off <<= 1) {
        double od = __shfl_xor(d, off, 64);
        int oi = __shfl_xor(idx, off, 64);
        bool better = (od < d) || (od == d && oi < idx);
        d = better ? od : d;
        idx = better ? oi : idx;
    }
    if (lane == 0) {
        out[(size_t)T_ROWS * D_DIM + 1 + row] = (float)idx;
        partials[row] = d;
    }
    float4 e = *reinterpret_cast<const float4*>(emb + (size_t)idx * D_DIM + lane * 4);
    *reinterpret_cast<float4*>(out + (size_t)row * D_DIM + lane * 4) = e;
}

// ---------------- final loss: deterministic fp64 reduce of 16384 row-losses ----------------
__global__ void k_loss_d(const double* __restrict__ partials, float* __restrict__ out) {
    double s = 0.0;
    const int t = threadIdx.x;
#pragma unroll
    for (int i = 0; i < 64; ++i) s += partials[t + 256 * i];
#pragma unroll
    for (int off = 32; off; off >>= 1) s += __shfl_xor(s, off, 64);
    __shared__ double sm[4];
    const int wv = t >> 6, lane = t & 63;
    if (lane == 0) sm[wv] = s;
    __syncthreads();
    if (t == 0) {
        const double tot = sm[0] + sm[1] + sm[2] + sm[3];
        out[(size_t)T_ROWS * D_DIM] = (float)(1.25 * tot / (double)((size_t)T_ROWS * D_DIM));
    }
}

// ================= fallback fp32 path (round-1, proven) =================
__global__ void k_enorm(const float* __restrict__ emb, float* __restrict__ enorm) {
    int wave = threadIdx.x >> 6, lane = threadIdx.x & 63;
    int row = blockIdx.x * 4 + wave;
    float4 v = *reinterpret_cast<const float4*>(emb + (size_t)row * D_DIM + lane * 4);
    float s = v.x * v.x + v.y * v.y + v.z * v.z + v.w * v.w;
#pragma unroll
    for (int off = 32; off; off >>= 1) s += __shfl_xor(s, off, 64);
    if (lane == 0) enorm[row] = s;
}

__global__ void k_init(u64* __restrict__ keys) {
    keys[blockIdx.x * blockDim.x + threadIdx.x] = ~0ull;
}

__global__ __launch_bounds__(256, 2)
void k_main_fp32(const float* __restrict__ x, const float* __restrict__ emb,
                 const float* __restrict__ enorm, u64* __restrict__ keys) {
    __shared__ float Xs[32][128];
    __shared__ float Es[32][128];
    __shared__ u64 red[128][16];

    const int tid = threadIdx.x;
    const int tx = tid & 15, ty = tid >> 4;
    const int m0 = (blockIdx.x >> 2) * 128;
    const int nbase = (blockIdx.x & 3) * (N_CODES / 4);

    float best[8];
    int bidx[8];
#pragma unroll
    for (int r = 0; r < 8; ++r) { best[r] = 3.4e38f; bidx[r] = 0; }

    for (int nc = 0; nc < (N_CODES / 4) / 128; ++nc) {
        const int n0 = nbase + nc * 128;
        float acc[8][8] = {};
        for (int k0 = 0; k0 < D_DIM; k0 += 32) {
            __syncthreads();
            {
                const int m = tid & 127, q = tid >> 7;
#pragma unroll
                for (int i = 0; i < 4; ++i) {
                    const int k4 = q * 4 + i * 8;
                    float4 v = *reinterpret_cast<const float4*>(
                        x + (size_t)(m0 + m) * D_DIM + k0 + k4);
                    Xs[k4 + 0][m] = v.x; Xs[k4 + 1][m] = v.y;
                    Xs[k4 + 2][m] = v.z; Xs[k4 + 3][m] = v.w;
                }
            }
            {
                const int kq = (tid & 7) * 4, nrow = tid >> 3;
#pragma unroll
                for (int i = 0; i < 4; ++i) {
                    const int n = i * 32 + nrow;
                    float4 v = *reinterpret_cast<const float4*>(
                        emb + (size_t)(n0 + n) * D_DIM + k0 + kq);
                    const int c = n ^ kq;
                    Es[kq + 0][c] = v.x; Es[kq + 1][c] = v.y;
                    Es[kq + 2][c] = v.z; Es[kq + 3][c] = v.w;
                }
            }
            __syncthreads();
#pragma unroll
            for (int kkx = 0; kkx < 32; ++kkx) {
                const int swz = kkx & 28;
                float4 xa = *reinterpret_cast<const float4*>(&Xs[kkx][ty * 4]);
                float4 xb = *reinterpret_cast<const float4*>(&Xs[kkx][64 + ty * 4]);
                const int cb = (tx * 4) ^ swz;
                float4 ea = *reinterpret_cast<const float4*>(&Es[kkx][cb]);
                float4 eb = *reinterpret_cast<const float4*>(&Es[kkx][64 + cb]);
                float xr[8] = {xa.x, xa.y, xa.z, xa.w, xb.x, xb.y, xb.z, xb.w};
                float ec[8] = {ea.x, ea.y, ea.z, ea.w, eb.x, eb.y, eb.z, eb.w};
#pragma unroll
                for (int r = 0; r < 8; ++r)
#pragma unroll
                    for (int c = 0; c < 8; ++c)
                        acc[r][c] = fmaf(xr[r], ec[c], acc[r][c]);
            }
        }
#pragma unroll
        for (int c = 0; c < 8; ++c) {
            const int ncol = n0 + ((c < 4) ? (tx * 4 + c) : (64 + tx * 4 + (c - 4)));
            const float en = enorm[ncol];
#pragma unroll
            for (int r = 0; r < 8; ++r) {
                const float score = fmaf(-2.0f, acc[r][c], en);
                if (score < best[r]) { best[r] = score; bidx[r] = ncol; }
            }
        }
    }
#pragma unroll
    for (int r = 0; r < 8; ++r) {
        const int row = (r < 4) ? (ty * 4 + r) : (64 + ty * 4 + (r - 4));
        unsigned u = __float_as_uint(best[r]);
        u = (u & 0x80000000u) ? ~u : (u | 0x80000000u);
        red[row][tx] = ((u64)u << 32) | (unsigned)bidx[r];
    }
    __syncthreads();
    if (tid < 128) {
        u64 k = red[tid][0];
#pragma unroll
        for (int t = 1; t < 16; ++t) { u64 v = red[tid][t]; k = (v < k) ? v : k; }
        atomicMin(&keys[m0 + tid], k);
    }
}

__global__ void k_out_fb(const float* __restrict__ x, const float* __restrict__ emb,
                         const u64* __restrict__ keys, float* __restrict__ out,
                         float* __restrict__ partials) {
    const int tid = threadIdx.x;
    const int m0 = blockIdx.x * 64;
    __shared__ int idx_s[64];
    if (tid < 64) {
        const u32 idx = (u32)keys[m0 + tid];
        idx_s[tid] = (int)idx;
        out[(size_t)T_ROWS * D_DIM + 1 + m0 + tid] = (float)idx;
    }
    __syncthreads();
    const int wave = tid >> 6, lane = tid & 63;
    float loss = 0.f;
#pragma unroll
    for (int i = 0; i < 16; ++i) {
        const int r = i * 4 + wave;
        const int row = m0 + r;
        const int idx = idx_s[r];
        float4 e  = *reinterpret_cast<const float4*>(emb + (size_t)idx * D_DIM + lane * 4);
        float4 xv = *reinterpret_cast<const float4*>(x + (size_t)row * D_DIM + lane * 4);
        *reinterpret_cast<float4*>(out + (size_t)row * D_DIM + lane * 4) = e;
        const float dx = e.x - xv.x, dy = e.y - xv.y, dz = e.z - xv.z, dw = e.w - xv.w;
        loss += dx * dx + dy * dy + dz * dz + dw * dw;
    }
#pragma unroll
    for (int off = 32; off; off >>= 1) loss += __shfl_xor(loss, off, 64);
    __shared__ float wl[4];
    if (lane == 0) wl[wave] = loss;
    __syncthreads();
    if (tid == 0) partials[blockIdx.x] = wl[0] + wl[1] + wl[2] + wl[3];
}

__global__ void k_loss_f(const float* __restrict__ partials, float* __restrict__ out) {
    double s = (double)partials[threadIdx.x];
#pragma unroll
    for (int off = 32; off; off >>= 1) s += __shfl_xor(s, off, 64);
    __shared__ double sm[4];
    const int wave = threadIdx.x >> 6, lane = threadIdx.x & 63;
    if (lane == 0) sm[wave] = s;
    __syncthreads();
    if (threadIdx.x == 0) {
        const double tot = sm[0] + sm[1] + sm[2] + sm[3];
        out[(size_t)T_ROWS * D_DIM] = (float)(1.25 * tot / (double)((size_t)T_ROWS * D_DIM));
    }
}

extern "C" void kernel_launch(void* const* d_in, const int* in_sizes, int n_in,
                              void* d_out, int out_size, void* d_ws, size_t ws_size,
                              hipStream_t stream) {
    const float* x = (const float*)d_in[0];
    const float* emb = (const float*)d_in[1];
    float* out = (float*)d_out;
    char* ws = (char*)d_ws;

    const size_t NEED = 4867072ull;
    if (ws_size >= NEED) {
        u16* Ef = (u16*)(ws + 0);                   // 4 MB
        float* enormP = (float*)(ws + 4194304);     // 32 KB
        u32* cand = (u32*)(ws + 4227072);           // 512 KB (16384 x 8)
        double* partials = (double*)(ws + 4751360); // 128 KB

        k_prep_emb<<<N_CODES / 4, 256, 0, stream>>>(emb, Ef, enormP);
        k_main_mfma<<<(T_ROWS / 128) * NSPLIT, 256, 0, stream>>>(x, Ef, enormP, cand);
        k_refine<<<T_ROWS / 4, 256, 0, stream>>>(x, emb, cand, out, partials);
        k_loss_d<<<1, 256, 0, stream>>>(partials, out);
    } else {
        float* enorm = (float*)(ws + 0);
        u64* keys = (u64*)(ws + 32768);
        float* partials = (float*)(ws + 163840);

        k_enorm<<<N_CODES / 4, 256, 0, stream>>>(emb, enorm);
        k_init<<<T_ROWS / 256, 256, 0, stream>>>(keys);
        k_main_fp32<<<(T_ROWS / 128) * 4, 256, 0, stream>>>(x, emb, enorm, keys);
        k_out_fb<<<T_ROWS / 64, 256, 0, stream>>>(x, emb, keys, out, partials);
        k_loss_f<<<1, 256, 0, stream>>>(partials, out);
    }
}